// Round 1
// baseline (17096.352 us; speedup 1.0000x reference)
//
#include <hip/hip_runtime.h>
#include <math.h>

#define NB 512
#define NN 256
#define LAP_INF 1e30f

// ---------------------------------------------------------------------------
// pad_mask layout detection: flag = 1 (int32), 2 (float32), 0 (bytes/bool8).
// Reads only the first 131072 bytes, which is in-bounds under every layout
// (bool8 buffer = 131072 B, int32 = 524288 B, float32 = 524288 B).
// ---------------------------------------------------------------------------
__global__ void detect_kernel(const unsigned int* __restrict__ pw,
                              int* __restrict__ flag) {
  __shared__ int notInt, notFloat;
  if (threadIdx.x == 0) { notInt = 0; notFloat = 0; }
  __syncthreads();
  int li = 0, lf = 0;
  for (int t = threadIdx.x; t < 32768; t += 256) {
    unsigned int w = pw[t];
    if (w > 1u) li = 1;                             // not plain 0/1 int32
    if (w != 0u && w != 0x3F800000u) lf = 1;        // not 0.0f/1.0f float32
  }
  if (li) atomicOr(&notInt, 1);
  if (lf) atomicOr(&notFloat, 1);
  __syncthreads();
  if (threadIdx.x == 0) flag[0] = (!notInt) ? 1 : ((!notFloat) ? 2 : 0);
}

// ---------------------------------------------------------------------------
// Transpose + sanitize: Pt[k][i][j] = nan_to_num(costs[k][j][i], 1e6 all).
// Coalesced both directions via 32x33 LDS tile. block (32,8), grid (8,8,512).
// ---------------------------------------------------------------------------
__global__ __launch_bounds__(256)
void transpose_kernel(const float* __restrict__ in, float* __restrict__ out) {
  __shared__ float tile[32][33];
  const int k = blockIdx.z;
  const float* A = in + ((size_t)k << 16);
  float* Bp = out + ((size_t)k << 16);
  const int tx = threadIdx.x, ty = threadIdx.y;
  const int i0 = blockIdx.x * 32;  // i = fast index of costs row
  const int j0 = blockIdx.y * 32;  // j = row index of costs
#pragma unroll
  for (int r = 0; r < 32; r += 8) {
    float x = A[(size_t)(j0 + ty + r) * NN + (i0 + tx)];
    tile[ty + r][tx] = isfinite(x) ? x : 1e6f;
  }
  __syncthreads();
#pragma unroll
  for (int r = 0; r < 32; r += 8) {
    Bp[(size_t)(i0 + ty + r) * NN + (j0 + tx)] = tile[tx][ty + r];
  }
}

// ---------------------------------------------------------------------------
// One wave64 per batch. Lane L owns columns 4L..4L+3 (v, shortest, pathrow,
// SC, row4col in registers). Row-indexed state (u, col4row) + scratch in LDS.
// Exactly mirrors the reference JV while-loops, including argmin first-index
// tie-break and float op order.
// ---------------------------------------------------------------------------
__global__ __launch_bounds__(64)
void lap_kernel(const float* __restrict__ costs, const void* __restrict__ pm,
                const int* __restrict__ flag, const float* __restrict__ Pt,
                int* __restrict__ out, int useT) {
  const int k = blockIdx.x;
  const int lane = threadIdx.x;

  __shared__ float u[NN];
  __shared__ float shortestL[NN];
  __shared__ int pathrowL[NN];
  __shared__ int col4row[NN];
  __shared__ int srList[NN];
  __shared__ unsigned char used[NN];

  // ---- n_k = popcount(pad_mask[k]) under detected layout ----
  const int fl = flag[0];
  int cnt4 = 0;
  if (fl == 1) {
    const int* p = ((const int*)pm) + k * NN;
#pragma unroll
    for (int q = 0; q < 4; ++q) cnt4 += (p[lane * 4 + q] != 0);
  } else if (fl == 2) {
    const float* p = ((const float*)pm) + k * NN;
#pragma unroll
    for (int q = 0; q < 4; ++q) cnt4 += (p[lane * 4 + q] != 0.0f);
  } else {
    const unsigned char* p = ((const unsigned char*)pm) + k * NN;
#pragma unroll
    for (int q = 0; q < 4; ++q) cnt4 += (p[lane * 4 + q] != 0);
  }
#pragma unroll
  for (int off = 32; off > 0; off >>= 1) cnt4 += __shfl_down(cnt4, off);
  const int n_k = __shfl(cnt4, 0);

  // per-lane column state (cols 4*lane+q)
  float vv[4] = {0.f, 0.f, 0.f, 0.f};
  int r4c[4] = {-1, -1, -1, -1};

  for (int t = lane; t < NN; t += 64) { u[t] = 0.f; col4row[t] = -1; }
  __syncthreads();

  const float* PtK = Pt + ((size_t)k << 16);
  const float* costK = costs + ((size_t)k << 16);

  for (int cur = 0; cur < NN; ++cur) {
    float sh[4] = {LAP_INF, LAP_INF, LAP_INF, LAP_INF};
    int pr[4] = {-1, -1, -1, -1};
    unsigned scm = 0;          // SC bits for this lane's 4 cols
    float minval = 0.f;
    int i = cur, sink = -1, cnt = 0;

    // ---- shortest augmenting path ----
    while (sink < 0) {
      if (lane == 0) srList[cnt] = i;
      cnt++;
      const float ui = u[i];

      float cc[4] = {0.f, 0.f, 0.f, 0.f};  // padded rows (i >= n_k) are 0
      if (i < n_k) {
        if (useT) {
          const float4 rv = *(const float4*)(PtK + (size_t)i * NN + lane * 4);
          cc[0] = rv.x; cc[1] = rv.y; cc[2] = rv.z; cc[3] = rv.w;
        } else {
#pragma unroll
          for (int q = 0; q < 4; ++q) {
            float x = costK[(size_t)(lane * 4 + q) * NN + i];
            cc[q] = isfinite(x) ? x : 1e6f;
          }
        }
      }

      float bestv = LAP_INF;
      int bestc = NN;
#pragma unroll
      for (int q = 0; q < 4; ++q) {
        // exact reference order: ((minval + cost) - u[i]) - v[j]
        float r = minval + cc[q];
        r = r - ui;
        r = r - vv[q];
        const bool sc = (scm >> q) & 1u;
        if (!sc && r < sh[q]) { sh[q] = r; pr[q] = i; }
        const float m = sc ? LAP_INF : sh[q];
        const int c = lane * 4 + q;
        if (m < bestv) { bestv = m; bestc = c; }   // keeps lowest q on ties
      }
      // wave argmin, first-index tie-break (matches jnp.argmin)
#pragma unroll
      for (int off = 32; off > 0; off >>= 1) {
        const float ov = __shfl_down(bestv, off);
        const int oc = __shfl_down(bestc, off);
        if (ov < bestv || (ov == bestv && oc < bestc)) { bestv = ov; bestc = oc; }
      }
      bestv = __shfl(bestv, 0);
      bestc = __shfl(bestc, 0);
      minval = bestv;
      const int js = bestc;
      const int owner = js >> 2, slot = js & 3;
      if (lane == owner) scm |= (1u << slot);
      // fetch row4col[js] from owner lane's registers
      const int sel = (slot == 0) ? r4c[0] : (slot == 1) ? r4c[1]
                    : (slot == 2) ? r4c[2] : r4c[3];
      const int nxt = __shfl(sel, owner);
      if (nxt < 0) sink = js; else i = nxt;
    }

    // publish column state for the scalar phases
#pragma unroll
    for (int q = 0; q < 4; ++q) {
      shortestL[lane * 4 + q] = sh[q];
      pathrowL[lane * 4 + q] = pr[q];
    }
    __syncthreads();

    // ---- dual updates (Crouse 2016) ----
    for (int t = lane; t < cnt; t += 64) {
      const int ri = srList[t];
      if (ri == cur) u[ri] = u[ri] + minval;
      else u[ri] = u[ri] + (minval - shortestL[col4row[ri]]);
    }
#pragma unroll
    for (int q = 0; q < 4; ++q)
      if ((scm >> q) & 1u) vv[q] = vv[q] - (minval - sh[q]);
    __syncthreads();

    // ---- augment along alternating path (wave-uniform) ----
    int j = sink;
    bool done = false;
    while (!done) {
      const int pi = pathrowL[j];
      if (lane == (j >> 2)) {
        const int s_ = j & 3;
        if (s_ == 0) r4c[0] = pi;
        else if (s_ == 1) r4c[1] = pi;
        else if (s_ == 2) r4c[2] = pi;
        else r4c[3] = pi;
      }
      const int jn = col4row[pi];
      __syncthreads();
      if (lane == 0) col4row[pi] = j;
      done = (pi == cur);
      j = jn;
      __syncthreads();
    }
  }

  // ---- output: valid rows get col4row; padded rows get unused cols asc ----
  __syncthreads();
  for (int t = lane; t < NN; t += 64) used[t] = 0;
  __syncthreads();
  for (int t = lane; t < NN; t += 64)
    if (t < n_k) used[col4row[t]] = 1;
  __syncthreads();
  int* outK = out + k * NN;
  for (int t = lane; t < NN; t += 64)
    if (t < n_k) outK[t] = col4row[t];
  if (lane == 0) {
    int pos = n_k;
    for (int c = 0; c < NN; ++c)
      if (!used[c]) outK[pos++] = c;
  }
}

extern "C" void kernel_launch(void* const* d_in, const int* in_sizes, int n_in,
                              void* d_out, int out_size, void* d_ws, size_t ws_size,
                              hipStream_t stream) {
  const float* costs = (const float*)d_in[0];
  const void* pm = d_in[1];
  int* out = (int*)d_out;

  int* flag = (int*)d_ws;
  float* Pt = (float*)((char*)d_ws + 256);
  const size_t need = 256 + (size_t)NB * NN * NN * sizeof(float);
  const int useT = (ws_size >= need) ? 1 : 0;

  detect_kernel<<<1, 256, 0, stream>>>((const unsigned int*)pm, flag);
  if (useT) {
    dim3 g(8, 8, NB), b(32, 8);
    transpose_kernel<<<g, b, 0, stream>>>(costs, Pt);
  }
  lap_kernel<<<NB, 64, 0, stream>>>(costs, pm, flag, useT ? Pt : costs, out, useT);
}

// Round 2
// 8816.640 us; speedup vs baseline: 1.9391x; 1.9391x over previous
//
#include <hip/hip_runtime.h>
#include <math.h>

#define NB 512
#define NN 256
#define NCACHE 58
#define LAP_INF 1e30f

// ---------------------------------------------------------------------------
// pad_mask layout detection: flag = 1 (int32), 2 (float32), 0 (bytes/bool8).
// ---------------------------------------------------------------------------
__global__ void detect_kernel(const unsigned int* __restrict__ pw,
                              int* __restrict__ flag) {
  __shared__ int notInt, notFloat;
  if (threadIdx.x == 0) { notInt = 0; notFloat = 0; }
  __syncthreads();
  int li = 0, lf = 0;
  for (int t = threadIdx.x; t < 32768; t += 256) {
    unsigned int w = pw[t];
    if (w > 1u) li = 1;
    if (w != 0u && w != 0x3F800000u) lf = 1;
  }
  if (li) atomicOr(&notInt, 1);
  if (lf) atomicOr(&notFloat, 1);
  __syncthreads();
  if (threadIdx.x == 0) flag[0] = (!notInt) ? 1 : ((!notFloat) ? 2 : 0);
}

// ---------------------------------------------------------------------------
// Transpose + sanitize: Pt[k][i][j] = nan_to_num(costs[k][j][i]).
// ---------------------------------------------------------------------------
__global__ __launch_bounds__(256)
void transpose_kernel(const float* __restrict__ in, float* __restrict__ out) {
  __shared__ float tile[32][33];
  const int k = blockIdx.z;
  const float* A = in + ((size_t)k << 16);
  float* Bp = out + ((size_t)k << 16);
  const int tx = threadIdx.x, ty = threadIdx.y;
  const int i0 = blockIdx.x * 32;
  const int j0 = blockIdx.y * 32;
#pragma unroll
  for (int r = 0; r < 32; r += 8) {
    float x = A[(size_t)(j0 + ty + r) * NN + (i0 + tx)];
    tile[ty + r][tx] = isfinite(x) ? x : 1e6f;
  }
  __syncthreads();
#pragma unroll
  for (int r = 0; r < 32; r += 8) {
    Bp[(size_t)(i0 + ty + r) * NN + (j0 + tx)] = tile[tx][ty + r];
  }
}

// ---------------------------------------------------------------------------
// DPP wave64 u32 min: quad_perm xor1/xor2, half-mirror, mirror, bcast15/31.
// VALU-rate steps (~4 cy each) vs ds_bpermute (~60 cy each).
// ---------------------------------------------------------------------------
template <int CTRL>
__device__ __forceinline__ unsigned dpp_min_step(unsigned x) {
  unsigned y = (unsigned)__builtin_amdgcn_update_dpp((int)x, (int)x, CTRL, 0xF, 0xF, false);
  return y < x ? y : x;
}
__device__ __forceinline__ unsigned wave_min_u32(unsigned x) {
  x = dpp_min_step<0xB1>(x);   // quad_perm [1,0,3,2]
  x = dpp_min_step<0x4E>(x);   // quad_perm [2,3,0,1]
  x = dpp_min_step<0x141>(x);  // row_half_mirror
  x = dpp_min_step<0x140>(x);  // row_mirror
  x = dpp_min_step<0x142>(x);  // row_bcast15
  x = dpp_min_step<0x143>(x);  // row_bcast31
  return (unsigned)__builtin_amdgcn_readlane((int)x, 63);
}

// Order- and equality-preserving bijection f32 <-> u32 (no NaNs present).
__device__ __forceinline__ unsigned f2o(float f) {
  unsigned x = __float_as_uint(f);
  return x ^ ((unsigned)((int)x >> 31) | 0x80000000u);
}
__device__ __forceinline__ float o2f(unsigned m) {
  unsigned x = (m & 0x80000000u) ? (m & 0x7FFFFFFFu) : ~m;
  return __uint_as_float(x);
}

// ---------------------------------------------------------------------------
// One wave64 per batch. Lane L owns columns 4L..4L+3 (v, shortest, pathrow,
// SC, row4col) and rows 4L..4L+3 (u, SR) in registers. First NCACHE rows of
// the transposed cost matrix cached in LDS. Exact reference float op order.
// ---------------------------------------------------------------------------
__global__ __launch_bounds__(64)
void lap_kernel(const float* __restrict__ costs, const void* __restrict__ pm,
                const int* __restrict__ flag, const float* __restrict__ Pt,
                int* __restrict__ out, int useT) {
  const int k = blockIdx.x;
  const int lane = threadIdx.x;

  __shared__ __align__(16) float rowCache[NCACHE][NN];
  __shared__ float shortestL[NN];
  __shared__ int pathrowL[NN];
  __shared__ int col4row[NN];
  __shared__ unsigned char used[NN];

  // ---- n_k = popcount(pad_mask[k]) under detected layout ----
  const int fl = flag[0];
  int cnt4 = 0;
  if (fl == 1) {
    const int* p = ((const int*)pm) + k * NN;
#pragma unroll
    for (int q = 0; q < 4; ++q) cnt4 += (p[lane * 4 + q] != 0);
  } else if (fl == 2) {
    const float* p = ((const float*)pm) + k * NN;
#pragma unroll
    for (int q = 0; q < 4; ++q) cnt4 += (p[lane * 4 + q] != 0.0f);
  } else {
    const unsigned char* p = ((const unsigned char*)pm) + k * NN;
#pragma unroll
    for (int q = 0; q < 4; ++q) cnt4 += (p[lane * 4 + q] != 0);
  }
#pragma unroll
  for (int off = 32; off > 0; off >>= 1) cnt4 += __shfl_down(cnt4, off);
  const int n_k = __shfl(cnt4, 0);

  const float* PtK = Pt + ((size_t)k << 16);
  const float* costK = costs + ((size_t)k << 16);

  // ---- fill LDS row cache ----
  if (useT) {
    const float4* s4 = (const float4*)PtK;
    float4* c4 = (float4*)rowCache;
    for (int t = lane; t < NCACHE * (NN / 4); t += 64) c4[t] = s4[t];
  } else {
    for (int e = lane; e < NCACHE * NN; e += 64) {
      const int i = e >> 8, j = e & 255;
      float x = costK[(size_t)j * NN + i];
      rowCache[i][j] = isfinite(x) ? x : 1e6f;
    }
  }

  // per-lane column state (cols 4L+q) and row state (rows 4L+q)
  float vv[4] = {0.f, 0.f, 0.f, 0.f};
  float uu[4] = {0.f, 0.f, 0.f, 0.f};
  int r4c[4] = {-1, -1, -1, -1};

  for (int t = lane; t < NN; t += 64) col4row[t] = -1;
  __syncthreads();

  for (int cur = 0; cur < NN; ++cur) {
    float sh[4] = {LAP_INF, LAP_INF, LAP_INF, LAP_INF};
    int pr[4] = {-1, -1, -1, -1};
    unsigned scm = 0;  // SC bits, this lane's 4 cols
    unsigned srm = 0;  // SR bits, this lane's 4 rows
    float minval = 0.f;
    int i = cur, sink = -1;

    // ---- shortest augmenting path ----
    while (sink < 0) {
      const int islot = i & 3, iowner = i >> 2;
      if (lane == iowner) srm |= (1u << islot);
      // u[i] from owner lane's registers (slot uniform)
      const float su = (islot == 0) ? uu[0] : (islot == 1) ? uu[1]
                     : (islot == 2) ? uu[2] : uu[3];
      const float ui = __int_as_float(
          __builtin_amdgcn_readlane(__float_as_int(su), iowner));

      float cc[4] = {0.f, 0.f, 0.f, 0.f};  // padded rows (i >= n_k) are 0
      if (i < n_k) {
        if (i < NCACHE) {
          const float4 rv = *(const float4*)(&rowCache[i][lane * 4]);
          cc[0] = rv.x; cc[1] = rv.y; cc[2] = rv.z; cc[3] = rv.w;
        } else if (useT) {
          const float4 rv = *(const float4*)(PtK + (size_t)i * NN + lane * 4);
          cc[0] = rv.x; cc[1] = rv.y; cc[2] = rv.z; cc[3] = rv.w;
        } else {
#pragma unroll
          for (int q = 0; q < 4; ++q) {
            float x = costK[(size_t)(lane * 4 + q) * NN + i];
            cc[q] = isfinite(x) ? x : 1e6f;
          }
        }
      }

      unsigned lbv = 0xFFFFFFFFu;
      int lbq = 0;
#pragma unroll
      for (int q = 0; q < 4; ++q) {
        // exact reference order: ((minval + cost) - u[i]) - v[j]
        float r = minval + cc[q];
        r = r - ui;
        r = r - vv[q];
        const bool sc = (scm >> q) & 1u;
        if (!sc && r < sh[q]) { sh[q] = r; pr[q] = i; }
        const unsigned m = sc ? 0xFFFFFFFFu : f2o(sh[q]);
        if (m < lbv) { lbv = m; lbq = q; }  // keeps lowest q on ties
      }
      const unsigned gv = wave_min_u32(lbv);
      minval = o2f(gv);
      const unsigned long long cmask = __ballot(lbv == gv);
      const int owner = __ffsll((unsigned long long)cmask) - 1;  // lowest lane = lowest col
      const int js = (owner << 2) + __builtin_amdgcn_readlane(lbq, owner);
      if (lane == owner) scm |= (1u << lbq);
      const int sel = (lbq == 0) ? r4c[0] : (lbq == 1) ? r4c[1]
                    : (lbq == 2) ? r4c[2] : r4c[3];
      const int nxt = __builtin_amdgcn_readlane(sel, owner);
      if (nxt < 0) sink = js; else i = nxt;
    }

    // publish column state for the scalar phases
#pragma unroll
    for (int q = 0; q < 4; ++q) {
      shortestL[lane * 4 + q] = sh[q];
      pathrowL[lane * 4 + q] = pr[q];
    }
    __syncthreads();

    // ---- dual updates (Crouse 2016) ----
#pragma unroll
    for (int q = 0; q < 4; ++q) {
      if ((srm >> q) & 1u) {
        const int row = lane * 4 + q;
        if (row == cur) uu[q] = uu[q] + minval;
        else uu[q] = uu[q] + (minval - shortestL[col4row[row]]);
      }
      if ((scm >> q) & 1u) vv[q] = vv[q] - (minval - sh[q]);
    }
    __syncthreads();

    // ---- augment along alternating path (wave-uniform) ----
    int j = sink;
    bool done = false;
    while (!done) {
      const int pi = pathrowL[j];
      if (lane == (j >> 2)) {
        const int s_ = j & 3;
        if (s_ == 0) r4c[0] = pi;
        else if (s_ == 1) r4c[1] = pi;
        else if (s_ == 2) r4c[2] = pi;
        else r4c[3] = pi;
      }
      const int jn = col4row[pi];
      __syncthreads();
      if (lane == 0) col4row[pi] = j;
      done = (pi == cur);
      j = jn;
      __syncthreads();
    }
  }

  // ---- output: valid rows get col4row; padded rows get unused cols asc ----
  __syncthreads();
  for (int t = lane; t < NN; t += 64) used[t] = 0;
  __syncthreads();
  for (int t = lane; t < NN; t += 64)
    if (t < n_k) used[col4row[t]] = 1;
  __syncthreads();
  int* outK = out + k * NN;
  for (int t = lane; t < NN; t += 64)
    if (t < n_k) outK[t] = col4row[t];
  if (lane == 0) {
    int pos = n_k;
    for (int c = 0; c < NN; ++c)
      if (!used[c]) outK[pos++] = c;
  }
}

extern "C" void kernel_launch(void* const* d_in, const int* in_sizes, int n_in,
                              void* d_out, int out_size, void* d_ws, size_t ws_size,
                              hipStream_t stream) {
  const float* costs = (const float*)d_in[0];
  const void* pm = d_in[1];
  int* out = (int*)d_out;

  int* flag = (int*)d_ws;
  float* Pt = (float*)((char*)d_ws + 256);
  const size_t need = 256 + (size_t)NB * NN * NN * sizeof(float);
  const int useT = (ws_size >= need) ? 1 : 0;

  detect_kernel<<<1, 256, 0, stream>>>((const unsigned int*)pm, flag);
  if (useT) {
    dim3 g(8, 8, NB), b(32, 8);
    transpose_kernel<<<g, b, 0, stream>>>(costs, Pt);
  }
  lap_kernel<<<NB, 64, 0, stream>>>(costs, pm, flag, useT ? Pt : costs, out, useT);
}

// Round 3
// 517.123 us; speedup vs baseline: 33.0605x; 17.0494x over previous
//
#include <hip/hip_runtime.h>
#include <math.h>

#define NB 512
#define NN 256
#define NCACHE 60
#define LAP_INF 1e30f

// ---------------------------------------------------------------------------
// pad_mask layout detection: flag = 1 (int32), 2 (float32), 0 (bytes/bool8).
// ---------------------------------------------------------------------------
__global__ void detect_kernel(const unsigned int* __restrict__ pw,
                              int* __restrict__ flag) {
  __shared__ int notInt, notFloat;
  if (threadIdx.x == 0) { notInt = 0; notFloat = 0; }
  __syncthreads();
  int li = 0, lf = 0;
  for (int t = threadIdx.x; t < 32768; t += 256) {
    unsigned int w = pw[t];
    if (w > 1u) li = 1;
    if (w != 0u && w != 0x3F800000u) lf = 1;
  }
  if (li) atomicOr(&notInt, 1);
  if (lf) atomicOr(&notFloat, 1);
  __syncthreads();
  if (threadIdx.x == 0) flag[0] = (!notInt) ? 1 : ((!notFloat) ? 2 : 0);
}

// ---------------------------------------------------------------------------
// Transpose + sanitize: Pt[k][i][j] = nan_to_num(costs[k][j][i]).
// ---------------------------------------------------------------------------
__global__ __launch_bounds__(256)
void transpose_kernel(const float* __restrict__ in, float* __restrict__ out) {
  __shared__ float tile[32][33];
  const int k = blockIdx.z;
  const float* A = in + ((size_t)k << 16);
  float* Bp = out + ((size_t)k << 16);
  const int tx = threadIdx.x, ty = threadIdx.y;
  const int i0 = blockIdx.x * 32;
  const int j0 = blockIdx.y * 32;
#pragma unroll
  for (int r = 0; r < 32; r += 8) {
    float x = A[(size_t)(j0 + ty + r) * NN + (i0 + tx)];
    tile[ty + r][tx] = isfinite(x) ? x : 1e6f;
  }
  __syncthreads();
#pragma unroll
  for (int r = 0; r < 32; r += 8) {
    Bp[(size_t)(i0 + ty + r) * NN + (j0 + tx)] = tile[tx][ty + r];
  }
}

// ---------------------------------------------------------------------------
// DPP wave64 u32 min (VALU-rate) + order/equality-preserving f32<->u32 map.
// ---------------------------------------------------------------------------
template <int CTRL>
__device__ __forceinline__ unsigned dpp_min_step(unsigned x) {
  unsigned y = (unsigned)__builtin_amdgcn_update_dpp((int)x, (int)x, CTRL, 0xF, 0xF, false);
  return y < x ? y : x;
}
__device__ __forceinline__ unsigned wave_min_u32(unsigned x) {
  x = dpp_min_step<0xB1>(x);   // quad_perm [1,0,3,2]
  x = dpp_min_step<0x4E>(x);   // quad_perm [2,3,0,1]
  x = dpp_min_step<0x141>(x);  // row_half_mirror
  x = dpp_min_step<0x140>(x);  // row_mirror
  x = dpp_min_step<0x142>(x);  // row_bcast15
  x = dpp_min_step<0x143>(x);  // row_bcast31
  return (unsigned)__builtin_amdgcn_readlane((int)x, 63);
}
__device__ __forceinline__ unsigned f2o(float f) {
  unsigned x = __float_as_uint(f);
  return x ^ ((unsigned)((int)x >> 31) | 0x80000000u);
}
__device__ __forceinline__ float o2f(unsigned m) {
  unsigned x = (m & 0x80000000u) ? (m & 0x7FFFFFFFu) : ~m;
  return __uint_as_float(x);
}
__device__ __forceinline__ int sel4(const int a[4], int s) {
  return (s == 0) ? a[0] : (s == 1) ? a[1] : (s == 2) ? a[2] : a[3];
}
__device__ __forceinline__ void set4(int a[4], int s, int v) {
  if (s == 0) a[0] = v; else if (s == 1) a[1] = v;
  else if (s == 2) a[2] = v; else a[3] = v;
}

// ---------------------------------------------------------------------------
// One wave64 per batch. Lane L owns columns 4L..4L+3 (v, shortest, pathrow,
// SC, row4col) and rows 4L..4L+3 (u, SR, col4row) in registers. Only the
// n_k REAL rows are solved: padded rows have constant (0) cost and cannot
// change the optimal assignment restricted to real rows; their output slots
// are the ascending unused columns (same as the reference's fill).
// ---------------------------------------------------------------------------
__global__ __launch_bounds__(64)
void lap_kernel(const float* __restrict__ costs, const void* __restrict__ pm,
                const int* __restrict__ flag, const float* __restrict__ Pt,
                int* __restrict__ out, int useT) {
  const int k = blockIdx.x;
  const int lane = threadIdx.x;

  __shared__ __align__(16) float rowCache[NCACHE][NN];
  __shared__ float shortestL[NN];
  __shared__ unsigned char used[NN];

  // ---- n_k = popcount(pad_mask[k]) under detected layout ----
  const int fl = flag[0];
  int cnt4 = 0;
  if (fl == 1) {
    const int* p = ((const int*)pm) + k * NN;
#pragma unroll
    for (int q = 0; q < 4; ++q) cnt4 += (p[lane * 4 + q] != 0);
  } else if (fl == 2) {
    const float* p = ((const float*)pm) + k * NN;
#pragma unroll
    for (int q = 0; q < 4; ++q) cnt4 += (p[lane * 4 + q] != 0.0f);
  } else {
    const unsigned char* p = ((const unsigned char*)pm) + k * NN;
#pragma unroll
    for (int q = 0; q < 4; ++q) cnt4 += (p[lane * 4 + q] != 0);
  }
#pragma unroll
  for (int off = 32; off > 0; off >>= 1) cnt4 += __shfl_down(cnt4, off);
  const int n_k = __shfl(cnt4, 0);

  const float* PtK = Pt + ((size_t)k << 16);
  const float* costK = costs + ((size_t)k << 16);

  // ---- fill LDS row cache ----
  if (useT) {
    const float4* s4 = (const float4*)PtK;
    float4* c4 = (float4*)rowCache;
    for (int t = lane; t < NCACHE * (NN / 4); t += 64) c4[t] = s4[t];
  } else {
    for (int e = lane; e < NCACHE * NN; e += 64) {
      const int i = e >> 8, j = e & 255;
      float x = costK[(size_t)j * NN + i];
      rowCache[i][j] = isfinite(x) ? x : 1e6f;
    }
  }

  // per-lane column state (cols 4L+q) and row state (rows 4L+q)
  float vv[4] = {0.f, 0.f, 0.f, 0.f};
  float uu[4] = {0.f, 0.f, 0.f, 0.f};
  int r4c[4] = {-1, -1, -1, -1};   // row4col, col-indexed
  int c4r[4] = {-1, -1, -1, -1};   // col4row, row-indexed
  __syncthreads();

  for (int cur = 0; cur < n_k; ++cur) {
    float sh[4] = {LAP_INF, LAP_INF, LAP_INF, LAP_INF};
    int pr[4] = {-1, -1, -1, -1};
    unsigned scm = 0;  // SC bits, this lane's 4 cols
    unsigned srm = 0;  // SR bits, this lane's 4 rows
    float minval = 0.f;
    int i = cur, sink = -1;

    // ---- shortest augmenting path ----
    while (sink < 0) {
      const int islot = i & 3, iowner = i >> 2;
      if (lane == iowner) srm |= (1u << islot);
      const float su = (islot == 0) ? uu[0] : (islot == 1) ? uu[1]
                     : (islot == 2) ? uu[2] : uu[3];
      const float ui = __int_as_float(
          __builtin_amdgcn_readlane(__float_as_int(su), iowner));

      float cc[4];
      if (i < NCACHE) {
        const float4 rv = *(const float4*)(&rowCache[i][lane * 4]);
        cc[0] = rv.x; cc[1] = rv.y; cc[2] = rv.z; cc[3] = rv.w;
      } else if (useT) {
        const float4 rv = *(const float4*)(PtK + (size_t)i * NN + lane * 4);
        cc[0] = rv.x; cc[1] = rv.y; cc[2] = rv.z; cc[3] = rv.w;
      } else {
#pragma unroll
        for (int q = 0; q < 4; ++q) {
          float x = costK[(size_t)(lane * 4 + q) * NN + i];
          cc[q] = isfinite(x) ? x : 1e6f;
        }
      }

      unsigned lbv = 0xFFFFFFFFu;
      int lbq = 0;
#pragma unroll
      for (int q = 0; q < 4; ++q) {
        // exact reference order: ((minval + cost) - u[i]) - v[j]
        float r = minval + cc[q];
        r = r - ui;
        r = r - vv[q];
        const bool sc = (scm >> q) & 1u;
        if (!sc && r < sh[q]) { sh[q] = r; pr[q] = i; }
        const unsigned m = sc ? 0xFFFFFFFFu : f2o(sh[q]);
        if (m < lbv) { lbv = m; lbq = q; }  // keeps lowest q on ties
      }
      const unsigned gv = wave_min_u32(lbv);
      minval = o2f(gv);
      const unsigned long long cmask = __ballot(lbv == gv);
      const int owner = __ffsll((unsigned long long)cmask) - 1;
      const int js = (owner << 2) + __builtin_amdgcn_readlane(lbq, owner);
      if (lane == owner) scm |= (1u << lbq);
      const int nxt = __builtin_amdgcn_readlane(sel4(r4c, js & 3), owner);
      if (nxt < 0) sink = js; else i = nxt;
    }

    // publish shortest for the dual update's per-lane dynamic gather
#pragma unroll
    for (int q = 0; q < 4; ++q) shortestL[lane * 4 + q] = sh[q];
    __syncthreads();

    // ---- dual updates (Crouse 2016) — all register/LDS-read local ----
#pragma unroll
    for (int q = 0; q < 4; ++q) {
      if ((srm >> q) & 1u) {
        const int row = lane * 4 + q;
        if (row == cur) uu[q] = uu[q] + minval;
        else uu[q] = uu[q] + (minval - shortestL[c4r[q]]);
      }
      if ((scm >> q) & 1u) vv[q] = vv[q] - (minval - sh[q]);
    }

    // ---- augment along alternating path: pure registers, no barriers ----
    int j = sink;
    bool done = false;
    while (!done) {
      const int pi = __builtin_amdgcn_readlane(sel4(pr, j & 3), j >> 2);
      if (lane == (j >> 2)) set4(r4c, j & 3, pi);
      const int jn = __builtin_amdgcn_readlane(sel4(c4r, pi & 3), pi >> 2);
      if (lane == (pi >> 2)) set4(c4r, pi & 3, j);
      done = (pi == cur);
      j = jn;
    }
    __syncthreads();  // shortestL reused next row-solve
  }

  // ---- output: valid rows get col4row; padded rows get unused cols asc ----
  for (int t = lane; t < NN; t += 64) used[t] = 0;
  __syncthreads();
#pragma unroll
  for (int q = 0; q < 4; ++q) {
    const int row = lane * 4 + q;
    if (row < n_k) used[c4r[q]] = 1;
  }
  __syncthreads();
  int* outK = out + k * NN;
#pragma unroll
  for (int q = 0; q < 4; ++q) {
    const int row = lane * 4 + q;
    if (row < n_k) outK[row] = c4r[q];
  }
  if (lane == 0) {
    int pos = n_k;
    for (int c = 0; c < NN; ++c)
      if (!used[c]) outK[pos++] = c;
  }
}

extern "C" void kernel_launch(void* const* d_in, const int* in_sizes, int n_in,
                              void* d_out, int out_size, void* d_ws, size_t ws_size,
                              hipStream_t stream) {
  const float* costs = (const float*)d_in[0];
  const void* pm = d_in[1];
  int* out = (int*)d_out;

  int* flag = (int*)d_ws;
  float* Pt = (float*)((char*)d_ws + 256);
  const size_t need = 256 + (size_t)NB * NN * NN * sizeof(float);
  const int useT = (ws_size >= need) ? 1 : 0;

  detect_kernel<<<1, 256, 0, stream>>>((const unsigned int*)pm, flag);
  if (useT) {
    dim3 g(8, 8, NB), b(32, 8);
    transpose_kernel<<<g, b, 0, stream>>>(costs, Pt);
  }
  lap_kernel<<<NB, 64, 0, stream>>>(costs, pm, flag, useT ? Pt : costs, out, useT);
}

// Round 4
// 480.573 us; speedup vs baseline: 35.5749x; 1.0761x over previous
//
#include <hip/hip_runtime.h>
#include <math.h>

#define NB 512
#define NN 256
#define NCACHE 60
#define LAP_INF 1e30f

// ws layout: flag @0, n_k array @1024 (2048 B), dummy @4096 (2048 B), Pt @8192
#define WS_NK_OFF 1024
#define WS_DUMMY_OFF 4096
#define WS_PT_OFF 8192

// ---------------------------------------------------------------------------
// pad_mask layout detection: flag = 1 (int32), 2 (float32), 0 (bytes/bool8).
// ---------------------------------------------------------------------------
__global__ __launch_bounds__(1024)
void detect_kernel(const unsigned int* __restrict__ pw, int* __restrict__ flag) {
  __shared__ int notInt, notFloat;
  if (threadIdx.x == 0) { notInt = 0; notFloat = 0; }
  __syncthreads();
  int li = 0, lf = 0;
  for (int t = threadIdx.x; t < 32768; t += 1024) {
    unsigned int w = pw[t];
    if (w > 1u) li = 1;
    if (w != 0u && w != 0x3F800000u) lf = 1;
  }
  if (li) atomicOr(&notInt, 1);
  if (lf) atomicOr(&notFloat, 1);
  __syncthreads();
  if (threadIdx.x == 0) flag[0] = (!notInt) ? 1 : ((!notFloat) ? 2 : 0);
}

// ---------------------------------------------------------------------------
// n_k[k] = popcount(pad_mask[k]) under detected layout. One wave per batch.
// ---------------------------------------------------------------------------
__global__ __launch_bounds__(64)
void nk_kernel(const void* __restrict__ pm, const int* __restrict__ flag,
               int* __restrict__ nk) {
  const int k = blockIdx.x;
  const int lane = threadIdx.x;
  const int fl = flag[0];
  int cnt4 = 0;
  if (fl == 1) {
    const int* p = ((const int*)pm) + k * NN;
#pragma unroll
    for (int q = 0; q < 4; ++q) cnt4 += (p[lane * 4 + q] != 0);
  } else if (fl == 2) {
    const float* p = ((const float*)pm) + k * NN;
#pragma unroll
    for (int q = 0; q < 4; ++q) cnt4 += (p[lane * 4 + q] != 0.0f);
  } else {
    const unsigned char* p = ((const unsigned char*)pm) + k * NN;
#pragma unroll
    for (int q = 0; q < 4; ++q) cnt4 += (p[lane * 4 + q] != 0);
  }
#pragma unroll
  for (int off = 32; off > 0; off >>= 1) cnt4 += __shfl_down(cnt4, off);
  if (lane == 0) nk[k] = cnt4;
}

// ---------------------------------------------------------------------------
// Transpose + sanitize, but ONLY rows i < max(n_k[k], NCACHE) of Pt — lap
// never reads beyond that (path rows are always real rows < n_k).
// ---------------------------------------------------------------------------
__global__ __launch_bounds__(256)
void transpose_kernel(const float* __restrict__ in, float* __restrict__ out,
                      const int* __restrict__ nk) {
  const int k = blockIdx.z;
  const int i0 = blockIdx.x * 32;
  int bnd = nk[k];
  bnd = bnd > NCACHE ? bnd : NCACHE;
  if (i0 >= bnd) return;
  __shared__ float tile[32][33];
  const float* A = in + ((size_t)k << 16);
  float* Bp = out + ((size_t)k << 16);
  const int tx = threadIdx.x, ty = threadIdx.y;
  const int j0 = blockIdx.y * 32;
#pragma unroll
  for (int r = 0; r < 32; r += 8) {
    float x = A[(size_t)(j0 + ty + r) * NN + (i0 + tx)];
    tile[ty + r][tx] = isfinite(x) ? x : 1e6f;
  }
  __syncthreads();
#pragma unroll
  for (int r = 0; r < 32; r += 8) {
    Bp[(size_t)(i0 + ty + r) * NN + (j0 + tx)] = tile[tx][ty + r];
  }
}

// ---------------------------------------------------------------------------
// DPP wave64 u32 min (VALU-rate) + order/equality-preserving f32<->u32 map.
// ---------------------------------------------------------------------------
template <int CTRL>
__device__ __forceinline__ unsigned dpp_min_step(unsigned x) {
  unsigned y = (unsigned)__builtin_amdgcn_update_dpp((int)x, (int)x, CTRL, 0xF, 0xF, false);
  return y < x ? y : x;
}
__device__ __forceinline__ unsigned wave_min_u32(unsigned x) {
  x = dpp_min_step<0xB1>(x);   // quad_perm [1,0,3,2]
  x = dpp_min_step<0x4E>(x);   // quad_perm [2,3,0,1]
  x = dpp_min_step<0x141>(x);  // row_half_mirror
  x = dpp_min_step<0x140>(x);  // row_mirror
  x = dpp_min_step<0x142>(x);  // row_bcast15
  x = dpp_min_step<0x143>(x);  // row_bcast31
  return (unsigned)__builtin_amdgcn_readlane((int)x, 63);
}
__device__ __forceinline__ unsigned f2o(float f) {
  unsigned x = __float_as_uint(f);
  return x ^ ((unsigned)((int)x >> 31) | 0x80000000u);
}
__device__ __forceinline__ float o2f(unsigned m) {
  unsigned x = (m & 0x80000000u) ? (m & 0x7FFFFFFFu) : ~m;
  return __uint_as_float(x);
}
__device__ __forceinline__ int sel4(const int a[4], int s) {
  return (s == 0) ? a[0] : (s == 1) ? a[1] : (s == 2) ? a[2] : a[3];
}
__device__ __forceinline__ void set4(int a[4], int s, int v) {
  if (s == 0) a[0] = v; else if (s == 1) a[1] = v;
  else if (s == 2) a[2] = v; else a[3] = v;
}

// ---------------------------------------------------------------------------
// One wave64 per batch. Lane L owns columns 4L..4L+3 (v, shortest, pathrow,
// SC, row4col) and rows 4L..4L+3 (u, SR, col4row) in registers. Rows < NCACHE
// in LDS; rows [NCACHE, n_k) bulk-warmed into this XCD's L2 up front so the
// serial path loop never eats an HBM-latency first touch.
// ---------------------------------------------------------------------------
__global__ __launch_bounds__(64)
void lap_kernel(const float* __restrict__ costs, const void* __restrict__ pm,
                const int* __restrict__ flag, const int* __restrict__ nkArr,
                const float* __restrict__ Pt, float* __restrict__ dummy,
                int* __restrict__ out, int useT) {
  const int k = blockIdx.x;
  const int lane = threadIdx.x;

  __shared__ __align__(16) float rowCache[NCACHE][NN];
  __shared__ float shortestL[NN];
  __shared__ unsigned char used[NN];

  const float* PtK = Pt + ((size_t)k << 16);
  const float* costK = costs + ((size_t)k << 16);

  int n_k;
  if (useT) {
    n_k = nkArr[k];
  } else {
    const int fl = flag[0];
    int cnt4 = 0;
    if (fl == 1) {
      const int* p = ((const int*)pm) + k * NN;
#pragma unroll
      for (int q = 0; q < 4; ++q) cnt4 += (p[lane * 4 + q] != 0);
    } else if (fl == 2) {
      const float* p = ((const float*)pm) + k * NN;
#pragma unroll
      for (int q = 0; q < 4; ++q) cnt4 += (p[lane * 4 + q] != 0.0f);
    } else {
      const unsigned char* p = ((const unsigned char*)pm) + k * NN;
#pragma unroll
      for (int q = 0; q < 4; ++q) cnt4 += (p[lane * 4 + q] != 0);
    }
#pragma unroll
    for (int off = 32; off > 0; off >>= 1) cnt4 += __shfl_down(cnt4, off);
    n_k = __shfl(cnt4, 0);
  }

  // ---- fill LDS row cache ----
  if (useT) {
    const float4* s4 = (const float4*)PtK;
    float4* c4 = (float4*)rowCache;
    for (int t = lane; t < NCACHE * (NN / 4); t += 64) c4[t] = s4[t];
  } else {
    for (int e = lane; e < NCACHE * NN; e += 64) {
      const int i = e >> 8, j = e & 255;
      float x = costK[(size_t)j * NN + i];
      rowCache[i][j] = isfinite(x) ? x : 1e6f;
    }
  }

  // ---- bulk L2 warm-up of rows [NCACHE, n_k): pipelined, off the chain ----
  if (useT) {
    float wa = 0.f, wb = 0.f, wc = 0.f, wd = 0.f;
    const float4* s4 = (const float4*)PtK;
    for (int t = NCACHE * 64 + lane; t < n_k * 64; t += 64) {
      const float4 rv = s4[t];
      wa += rv.x; wb += rv.y; wc += rv.z; wd += rv.w;
    }
    // un-DCE-able sink (ws scratch, consumed by nothing)
    if (lane == 0) dummy[k] = wa + wb + wc + wd;
  }

  // per-lane column state (cols 4L+q) and row state (rows 4L+q)
  float vv[4] = {0.f, 0.f, 0.f, 0.f};
  float uu[4] = {0.f, 0.f, 0.f, 0.f};
  int r4c[4] = {-1, -1, -1, -1};   // row4col, col-indexed
  int c4r[4] = {-1, -1, -1, -1};   // col4row, row-indexed
  __syncthreads();

  for (int cur = 0; cur < n_k; ++cur) {
    float sh[4] = {LAP_INF, LAP_INF, LAP_INF, LAP_INF};
    int pr[4] = {-1, -1, -1, -1};
    unsigned scm = 0;  // SC bits, this lane's 4 cols
    unsigned srm = 0;  // SR bits, this lane's 4 rows
    float minval = 0.f;
    int i = cur, sink = -1;

    // ---- shortest augmenting path ----
    while (sink < 0) {
      const int islot = i & 3, iowner = i >> 2;
      if (lane == iowner) srm |= (1u << islot);
      const float su = (islot == 0) ? uu[0] : (islot == 1) ? uu[1]
                     : (islot == 2) ? uu[2] : uu[3];
      const float ui = __int_as_float(
          __builtin_amdgcn_readlane(__float_as_int(su), iowner));

      float cc[4];
      if (i < NCACHE) {
        const float4 rv = *(const float4*)(&rowCache[i][lane * 4]);
        cc[0] = rv.x; cc[1] = rv.y; cc[2] = rv.z; cc[3] = rv.w;
      } else if (useT) {
        const float4 rv = *(const float4*)(PtK + (size_t)i * NN + lane * 4);
        cc[0] = rv.x; cc[1] = rv.y; cc[2] = rv.z; cc[3] = rv.w;
      } else {
#pragma unroll
        for (int q = 0; q < 4; ++q) {
          float x = costK[(size_t)(lane * 4 + q) * NN + i];
          cc[q] = isfinite(x) ? x : 1e6f;
        }
      }

      unsigned lbv = 0xFFFFFFFFu;
      int lbq = 0;
#pragma unroll
      for (int q = 0; q < 4; ++q) {
        // exact reference order: ((minval + cost) - u[i]) - v[j]
        float r = minval + cc[q];
        r = r - ui;
        r = r - vv[q];
        const bool sc = (scm >> q) & 1u;
        if (!sc && r < sh[q]) { sh[q] = r; pr[q] = i; }
        const unsigned m = sc ? 0xFFFFFFFFu : f2o(sh[q]);
        if (m < lbv) { lbv = m; lbq = q; }  // keeps lowest q on ties
      }
      const unsigned gv = wave_min_u32(lbv);
      minval = o2f(gv);
      const unsigned long long cmask = __ballot(lbv == gv);
      const int owner = __ffsll((unsigned long long)cmask) - 1;
      const int js = (owner << 2) + __builtin_amdgcn_readlane(lbq, owner);
      if (lane == owner) scm |= (1u << lbq);
      const int nxt = __builtin_amdgcn_readlane(sel4(r4c, js & 3), owner);
      if (nxt < 0) sink = js; else i = nxt;
    }

    // publish shortest for the dual update's per-lane dynamic gather
#pragma unroll
    for (int q = 0; q < 4; ++q) shortestL[lane * 4 + q] = sh[q];
    __syncthreads();

    // ---- dual updates (Crouse 2016) ----
#pragma unroll
    for (int q = 0; q < 4; ++q) {
      if ((srm >> q) & 1u) {
        const int row = lane * 4 + q;
        if (row == cur) uu[q] = uu[q] + minval;
        else uu[q] = uu[q] + (minval - shortestL[c4r[q]]);
      }
      if ((scm >> q) & 1u) vv[q] = vv[q] - (minval - sh[q]);
    }

    // ---- augment along alternating path: pure registers, no barriers ----
    int j = sink;
    bool done = false;
    while (!done) {
      const int pi = __builtin_amdgcn_readlane(sel4(pr, j & 3), j >> 2);
      if (lane == (j >> 2)) set4(r4c, j & 3, pi);
      const int jn = __builtin_amdgcn_readlane(sel4(c4r, pi & 3), pi >> 2);
      if (lane == (pi >> 2)) set4(c4r, pi & 3, j);
      done = (pi == cur);
      j = jn;
    }
    __syncthreads();  // shortestL reused next row-solve
  }

  // ---- output: valid rows get col4row; padded rows get unused cols asc ----
  for (int t = lane; t < NN; t += 64) used[t] = 0;
  __syncthreads();
#pragma unroll
  for (int q = 0; q < 4; ++q) {
    const int row = lane * 4 + q;
    if (row < n_k) used[c4r[q]] = 1;
  }
  __syncthreads();
  int* outK = out + k * NN;
#pragma unroll
  for (int q = 0; q < 4; ++q) {
    const int row = lane * 4 + q;
    if (row < n_k) outK[row] = c4r[q];
  }
  if (lane == 0) {
    int pos = n_k;
    for (int c = 0; c < NN; ++c)
      if (!used[c]) outK[pos++] = c;
  }
}

extern "C" void kernel_launch(void* const* d_in, const int* in_sizes, int n_in,
                              void* d_out, int out_size, void* d_ws, size_t ws_size,
                              hipStream_t stream) {
  const float* costs = (const float*)d_in[0];
  const void* pm = d_in[1];
  int* out = (int*)d_out;

  int* flag = (int*)d_ws;
  int* nk = (int*)((char*)d_ws + WS_NK_OFF);
  float* dummy = (float*)((char*)d_ws + WS_DUMMY_OFF);
  float* Pt = (float*)((char*)d_ws + WS_PT_OFF);
  const size_t need = WS_PT_OFF + (size_t)NB * NN * NN * sizeof(float);
  const int useT = (ws_size >= need) ? 1 : 0;

  detect_kernel<<<1, 1024, 0, stream>>>((const unsigned int*)pm, flag);
  nk_kernel<<<NB, 64, 0, stream>>>(pm, flag, nk);
  if (useT) {
    dim3 g(8, 8, NB), b(32, 8);
    transpose_kernel<<<g, b, 0, stream>>>(costs, Pt, nk);
  }
  lap_kernel<<<NB, 64, 0, stream>>>(costs, pm, flag, nk, useT ? Pt : costs,
                                    dummy, out, useT);
}

// Round 5
// 412.155 us; speedup vs baseline: 41.4804x; 1.1660x over previous
//
#include <hip/hip_runtime.h>
#include <math.h>

#define NB 512
#define NN 256
#define NCACHE 60
#define LAP_INF 1e30f

// ws layout: flag @0, n_k array @1024, Pt @8192
#define WS_NK_OFF 1024
#define WS_PT_OFF 8192

// ---------------------------------------------------------------------------
// pad_mask layout detection: flag = 1 (int32), 2 (float32), 0 (bytes/bool8).
// Reads only the first 131072 bytes (in-bounds under every layout).
// ---------------------------------------------------------------------------
__global__ __launch_bounds__(1024)
void detect_kernel(const unsigned int* __restrict__ pw, int* __restrict__ flag) {
  __shared__ int notInt, notFloat;
  if (threadIdx.x == 0) { notInt = 0; notFloat = 0; }
  __syncthreads();
  int li = 0, lf = 0;
  for (int t = threadIdx.x; t < 32768; t += 1024) {
    unsigned int w = pw[t];
    if (w > 1u) li = 1;
    if (w != 0u && w != 0x3F800000u) lf = 1;
  }
  if (li) atomicOr(&notInt, 1);
  if (lf) atomicOr(&notFloat, 1);
  __syncthreads();
  if (threadIdx.x == 0) flag[0] = (!notInt) ? 1 : ((!notFloat) ? 2 : 0);
}

// ---------------------------------------------------------------------------
// n_k[k] = popcount(pad_mask[k]) under detected layout. One wave per batch.
// ---------------------------------------------------------------------------
__global__ __launch_bounds__(64)
void nk_kernel(const void* __restrict__ pm, const int* __restrict__ flag,
               int* __restrict__ nk) {
  const int k = blockIdx.x;
  const int lane = threadIdx.x;
  const int fl = flag[0];
  int cnt4 = 0;
  if (fl == 1) {
    const int* p = ((const int*)pm) + k * NN;
#pragma unroll
    for (int q = 0; q < 4; ++q) cnt4 += (p[lane * 4 + q] != 0);
  } else if (fl == 2) {
    const float* p = ((const float*)pm) + k * NN;
#pragma unroll
    for (int q = 0; q < 4; ++q) cnt4 += (p[lane * 4 + q] != 0.0f);
  } else {
    const unsigned char* p = ((const unsigned char*)pm) + k * NN;
#pragma unroll
    for (int q = 0; q < 4; ++q) cnt4 += (p[lane * 4 + q] != 0);
  }
#pragma unroll
  for (int off = 32; off > 0; off >>= 1) cnt4 += __shfl_down(cnt4, off);
  if (lane == 0) nk[k] = cnt4;
}

// ---------------------------------------------------------------------------
// Transpose + sanitize ONLY rows i < max(n_k[k], NCACHE) of Pt.
// ---------------------------------------------------------------------------
__global__ __launch_bounds__(256)
void transpose_kernel(const float* __restrict__ in, float* __restrict__ out,
                      const int* __restrict__ nk) {
  const int k = blockIdx.z;
  const int i0 = blockIdx.x * 32;
  int bnd = nk[k];
  bnd = bnd > NCACHE ? bnd : NCACHE;
  if (i0 >= bnd) return;
  __shared__ float tile[32][33];
  const float* A = in + ((size_t)k << 16);
  float* Bp = out + ((size_t)k << 16);
  const int tx = threadIdx.x, ty = threadIdx.y;
  const int j0 = blockIdx.y * 32;
#pragma unroll
  for (int r = 0; r < 32; r += 8) {
    float x = A[(size_t)(j0 + ty + r) * NN + (i0 + tx)];
    tile[ty + r][tx] = isfinite(x) ? x : 1e6f;
  }
  __syncthreads();
#pragma unroll
  for (int r = 0; r < 32; r += 8) {
    Bp[(size_t)(i0 + ty + r) * NN + (j0 + tx)] = tile[tx][ty + r];
  }
}

// ---------------------------------------------------------------------------
// DPP wave64 u32 min (VALU-rate) + order/equality-preserving f32<->u32 map.
// ---------------------------------------------------------------------------
template <int CTRL>
__device__ __forceinline__ unsigned dpp_min_step(unsigned x) {
  unsigned y = (unsigned)__builtin_amdgcn_update_dpp((int)x, (int)x, CTRL, 0xF, 0xF, false);
  return y < x ? y : x;
}
__device__ __forceinline__ unsigned wave_min_u32(unsigned x) {
  x = dpp_min_step<0xB1>(x);   // quad_perm [1,0,3,2]
  x = dpp_min_step<0x4E>(x);   // quad_perm [2,3,0,1]
  x = dpp_min_step<0x141>(x);  // row_half_mirror
  x = dpp_min_step<0x140>(x);  // row_mirror
  x = dpp_min_step<0x142>(x);  // row_bcast15
  x = dpp_min_step<0x143>(x);  // row_bcast31
  return (unsigned)__builtin_amdgcn_readlane((int)x, 63);
}
__device__ __forceinline__ unsigned f2o(float f) {
  unsigned x = __float_as_uint(f);
  return x ^ ((unsigned)((int)x >> 31) | 0x80000000u);
}
__device__ __forceinline__ float o2f(unsigned m) {
  unsigned x = (m & 0x80000000u) ? (m & 0x7FFFFFFFu) : ~m;
  return __uint_as_float(x);
}
__device__ __forceinline__ int sel4(const int a[4], int s) {
  return (s == 0) ? a[0] : (s == 1) ? a[1] : (s == 2) ? a[2] : a[3];
}
__device__ __forceinline__ void set4(int a[4], int s, int v) {
  if (s == 0) a[0] = v; else if (s == 1) a[1] = v;
  else if (s == 2) a[2] = v; else a[3] = v;
}
__device__ __forceinline__ void setf4(float a[4], int s, float v) {
  if (s == 0) a[0] = v; else if (s == 1) a[1] = v;
  else if (s == 2) a[2] = v; else a[3] = v;
}

// ---------------------------------------------------------------------------
// One wave64 per batch. Lane L owns columns 4L..4L+3 (v, shortest, pathrow,
// SC, row4col) and rows 4L..4L+3 (u, SR, col4row) in registers.
// Phase 1 (JV row reduction): u[r] = row min; greedily assign if the argmin
// column is free. Dual-feasible, tight on assigned pairs. Sequential row
// scans -> software-prefetch the next global row.
// Phase 2: shortest augmenting path for the ~10-20% leftover free rows.
// Final assignment equals the reference's (unique optimum; validated R2/R3).
// ---------------------------------------------------------------------------
__global__ __launch_bounds__(64)
void lap_kernel(const float* __restrict__ costs, const void* __restrict__ pm,
                const int* __restrict__ flag, const int* __restrict__ nkArr,
                const float* __restrict__ Pt, int* __restrict__ out, int useT) {
  const int k = blockIdx.x;
  const int lane = threadIdx.x;

  __shared__ __align__(16) float rowCache[NCACHE][NN];
  __shared__ float shortestL[NN];
  __shared__ int freeRowsL[NN];
  __shared__ unsigned char used[NN];

  const float* PtK = Pt + ((size_t)k << 16);
  const float* costK = costs + ((size_t)k << 16);

  int n_k;
  if (useT) {
    n_k = nkArr[k];
  } else {
    const int fl = flag[0];
    int cnt4 = 0;
    if (fl == 1) {
      const int* p = ((const int*)pm) + k * NN;
#pragma unroll
      for (int q = 0; q < 4; ++q) cnt4 += (p[lane * 4 + q] != 0);
    } else if (fl == 2) {
      const float* p = ((const float*)pm) + k * NN;
#pragma unroll
      for (int q = 0; q < 4; ++q) cnt4 += (p[lane * 4 + q] != 0.0f);
    } else {
      const unsigned char* p = ((const unsigned char*)pm) + k * NN;
#pragma unroll
      for (int q = 0; q < 4; ++q) cnt4 += (p[lane * 4 + q] != 0);
    }
#pragma unroll
    for (int off = 32; off > 0; off >>= 1) cnt4 += __shfl_down(cnt4, off);
    n_k = __shfl(cnt4, 0);
  }

  // ---- fill LDS row cache ----
  if (useT) {
    const float4* s4 = (const float4*)PtK;
    float4* c4 = (float4*)rowCache;
    for (int t = lane; t < NCACHE * (NN / 4); t += 64) c4[t] = s4[t];
  } else {
    for (int e = lane; e < NCACHE * NN; e += 64) {
      const int i = e >> 8, j = e & 255;
      float x = costK[(size_t)j * NN + i];
      rowCache[i][j] = isfinite(x) ? x : 1e6f;
    }
  }

  float vv[4] = {0.f, 0.f, 0.f, 0.f};
  float uu[4] = {0.f, 0.f, 0.f, 0.f};
  int r4c[4] = {-1, -1, -1, -1};   // row4col, col-indexed
  int c4r[4] = {-1, -1, -1, -1};   // col4row, row-indexed
  int nfree = 0;                    // wave-uniform
  __syncthreads();

  // ---- phase 1: greedy row reduction, prefetched sequential scans ----
  float4 carry = {0.f, 0.f, 0.f, 0.f};
  for (int r = 0; r < n_k; ++r) {
    float cc[4];
    if (r < NCACHE) {
      const float4 rv = *(const float4*)(&rowCache[r][lane * 4]);
      cc[0] = rv.x; cc[1] = rv.y; cc[2] = rv.z; cc[3] = rv.w;
    } else if (useT) {
      cc[0] = carry.x; cc[1] = carry.y; cc[2] = carry.z; cc[3] = carry.w;
    } else {
#pragma unroll
      for (int q = 0; q < 4; ++q) {
        float x = costK[(size_t)(lane * 4 + q) * NN + r];
        cc[q] = isfinite(x) ? x : 1e6f;
      }
    }
    // prefetch next global row (sequential, known address)
    if (useT && r + 1 >= NCACHE && r + 1 < n_k)
      carry = *(const float4*)(PtK + (size_t)(r + 1) * NN + lane * 4);

    unsigned lbv = 0xFFFFFFFFu;
    int lbq = 0;
#pragma unroll
    for (int q = 0; q < 4; ++q) {
      const unsigned m = f2o(cc[q]);
      if (m < lbv) { lbv = m; lbq = q; }
    }
    const unsigned gv = wave_min_u32(lbv);
    const unsigned long long cmask = __ballot(lbv == gv);
    const int owner = __ffsll((unsigned long long)cmask) - 1;
    const int js = (owner << 2) + __builtin_amdgcn_readlane(lbq, owner);
    // u[r] = row minimum (dual-feasible, tight at js)
    if (lane == (r >> 2)) setf4(uu, r & 3, o2f(gv));
    const int occ = __builtin_amdgcn_readlane(sel4(r4c, js & 3), owner);
    if (occ < 0) {
      if (lane == owner) set4(r4c, js & 3, r);
      if (lane == (r >> 2)) set4(c4r, r & 3, js);
    } else {
      if (lane == 0) freeRowsL[nfree] = r;
      nfree++;
    }
  }
  __syncthreads();  // freeRowsL visible

  // ---- phase 2: shortest augmenting path for leftover free rows ----
  for (int t = 0; t < nfree; ++t) {
    const int cur = freeRowsL[t];
    float sh[4] = {LAP_INF, LAP_INF, LAP_INF, LAP_INF};
    int pr[4] = {-1, -1, -1, -1};
    unsigned scm = 0;  // SC bits, this lane's 4 cols
    unsigned srm = 0;  // SR bits, this lane's 4 rows
    float minval = 0.f;
    int i = cur, sink = -1;

    while (sink < 0) {
      const int islot = i & 3, iowner = i >> 2;
      if (lane == iowner) srm |= (1u << islot);
      const float su = (islot == 0) ? uu[0] : (islot == 1) ? uu[1]
                     : (islot == 2) ? uu[2] : uu[3];
      const float ui = __int_as_float(
          __builtin_amdgcn_readlane(__float_as_int(su), iowner));

      float cc[4];
      if (i < NCACHE) {
        const float4 rv = *(const float4*)(&rowCache[i][lane * 4]);
        cc[0] = rv.x; cc[1] = rv.y; cc[2] = rv.z; cc[3] = rv.w;
      } else if (useT) {
        const float4 rv = *(const float4*)(PtK + (size_t)i * NN + lane * 4);
        cc[0] = rv.x; cc[1] = rv.y; cc[2] = rv.z; cc[3] = rv.w;
      } else {
#pragma unroll
        for (int q = 0; q < 4; ++q) {
          float x = costK[(size_t)(lane * 4 + q) * NN + i];
          cc[q] = isfinite(x) ? x : 1e6f;
        }
      }

      unsigned lbv = 0xFFFFFFFFu;
      int lbq = 0;
#pragma unroll
      for (int q = 0; q < 4; ++q) {
        // exact reference order: ((minval + cost) - u[i]) - v[j]
        float r = minval + cc[q];
        r = r - ui;
        r = r - vv[q];
        const bool sc = (scm >> q) & 1u;
        if (!sc && r < sh[q]) { sh[q] = r; pr[q] = i; }
        const unsigned m = sc ? 0xFFFFFFFFu : f2o(sh[q]);
        if (m < lbv) { lbv = m; lbq = q; }
      }
      const unsigned gv = wave_min_u32(lbv);
      minval = o2f(gv);
      const unsigned long long cmask = __ballot(lbv == gv);
      const int owner = __ffsll((unsigned long long)cmask) - 1;
      const int js = (owner << 2) + __builtin_amdgcn_readlane(lbq, owner);
      if (lane == owner) scm |= (1u << lbq);
      const int nxt = __builtin_amdgcn_readlane(sel4(r4c, js & 3), owner);
      if (nxt < 0) sink = js; else i = nxt;
    }

    // publish shortest for the dual update's dynamic gather
#pragma unroll
    for (int q = 0; q < 4; ++q) shortestL[lane * 4 + q] = sh[q];
    __syncthreads();

    // ---- dual updates (Crouse 2016) ----
#pragma unroll
    for (int q = 0; q < 4; ++q) {
      if ((srm >> q) & 1u) {
        const int row = lane * 4 + q;
        if (row == cur) uu[q] = uu[q] + minval;
        else uu[q] = uu[q] + (minval - shortestL[c4r[q]]);
      }
      if ((scm >> q) & 1u) vv[q] = vv[q] - (minval - sh[q]);
    }

    // ---- augment along alternating path: pure registers ----
    int j = sink;
    bool done = false;
    while (!done) {
      const int pi = __builtin_amdgcn_readlane(sel4(pr, j & 3), j >> 2);
      if (lane == (j >> 2)) set4(r4c, j & 3, pi);
      const int jn = __builtin_amdgcn_readlane(sel4(c4r, pi & 3), pi >> 2);
      if (lane == (pi >> 2)) set4(c4r, pi & 3, j);
      done = (pi == cur);
      j = jn;
    }
    __syncthreads();  // shortestL reused next path
  }

  // ---- output: valid rows get col4row; padded rows get unused cols asc ----
  for (int t = lane; t < NN; t += 64) used[t] = 0;
  __syncthreads();
#pragma unroll
  for (int q = 0; q < 4; ++q) {
    const int row = lane * 4 + q;
    if (row < n_k) used[c4r[q]] = 1;
  }
  __syncthreads();
  int* outK = out + k * NN;
#pragma unroll
  for (int q = 0; q < 4; ++q) {
    const int row = lane * 4 + q;
    if (row < n_k) outK[row] = c4r[q];
  }
  if (lane == 0) {
    int pos = n_k;
    for (int c = 0; c < NN; ++c)
      if (!used[c]) outK[pos++] = c;
  }
}

extern "C" void kernel_launch(void* const* d_in, const int* in_sizes, int n_in,
                              void* d_out, int out_size, void* d_ws, size_t ws_size,
                              hipStream_t stream) {
  const float* costs = (const float*)d_in[0];
  const void* pm = d_in[1];
  int* out = (int*)d_out;

  int* flag = (int*)d_ws;
  int* nk = (int*)((char*)d_ws + WS_NK_OFF);
  float* Pt = (float*)((char*)d_ws + WS_PT_OFF);
  const size_t need = WS_PT_OFF + (size_t)NB * NN * NN * sizeof(float);
  const int useT = (ws_size >= need) ? 1 : 0;

  detect_kernel<<<1, 1024, 0, stream>>>((const unsigned int*)pm, flag);
  nk_kernel<<<NB, 64, 0, stream>>>(pm, flag, nk);
  if (useT) {
    dim3 g(8, 8, NB), b(32, 8);
    transpose_kernel<<<g, b, 0, stream>>>(costs, Pt, nk);
  }
  lap_kernel<<<NB, 64, 0, stream>>>(costs, pm, flag, nk, useT ? Pt : costs,
                                    out, useT);
}